// Round 9
// baseline (218.704 us; speedup 1.0000x reference)
//
#include <hip/hip_runtime.h>

#define DIM 768
#define NHEADS 12
#define HDIM 64
#define BATCH 2
#define SEQ 2048
#define ROWS (BATCH*SEQ)   // 4096

typedef __attribute__((ext_vector_type(8))) _Float16 f16x8;
typedef __attribute__((ext_vector_type(4))) _Float16 f16x4;
typedef __attribute__((ext_vector_type(4))) float    f32x4;

// async global->LDS DMA, 16 B per lane; LDS dest must be wave-uniform base
__device__ __forceinline__ void dma16(const _Float16* g, _Float16* l) {
    __builtin_amdgcn_global_load_lds(
        (const __attribute__((address_space(1))) unsigned int*)g,
        (__attribute__((address_space(3))) unsigned int*)l, 16, 0, 0);
}

// ============================================================
// Fragment layout F(mt, kt): 16 rows x 32 cols of row-major M[R][C]:
//   frag[lane][j] = M[mt*16 + (lane&15)][kt*32 + (lane>>4)*8 + j]
// stored at dst[((mt*(C/32) + kt)*64 + lane)*8] (halves).
// V tile layout (for 16x16x16 PV MFMA): per 16-key chunk kc,
//   Vkt[((kc*48 + (h*4+dt))*64 + lane)*4] : tile[lane][j] =
//   V[d = (h*4+dt)*16 + (lane&15)][key = kc*16 + (lane>>4)*4 + j]
// Lc tile layout (f32): Lc[((qt16*128 + kk)*64 + lane)*4 + r] holds
//   log2(D[q,k]) + log2(sqrt(768)) for (k = kk*16 + quad*4 + r, q = qt*16+c)
//   -- identical lane mapping to the S^T MFMA output, so pass 2 reads it
//   as one b128 per subtile with zero rearrangement.
// ============================================================

// ---- all 4 fp32->f16 frag conversions in one launch (all have C=768) ----
// Wq is pre-scaled by log2(e): QK^T scores land in log2 domain, so the
// softmax exp is a single v_exp_f32 (2^x). Wq feeds ONLY Q. (verified v4/v5)
__global__ __launch_bounds__(256) void cvt_all(
    const float* __restrict__ x,  const float* __restrict__ wq,
    const float* __restrict__ wk, const float* __restrict__ wv,
    _Float16* __restrict__ xf,  _Float16* __restrict__ wqf,
    _Float16* __restrict__ wkf, _Float16* __restrict__ wvf)
{
    const int lane = threadIdx.x & 63;
    const int wid  = (blockIdx.x * 256 + threadIdx.x) >> 6;
    const float* src; _Float16* dst; int t;
    float sc = 1.0f;
    if (wid < 6144)      { src = x;  dst = xf;  t = wid;        }
    else if (wid < 7296) { src = wq; dst = wqf; t = wid - 6144; sc = 1.4426950408889634f; }
    else if (wid < 8448) { src = wk; dst = wkf; t = wid - 7296; }
    else                 { src = wv; dst = wvf; t = wid - 8448; }
    const int c = lane & 15, quad = lane >> 4;
    const int mt = t / 24, kt = t % 24;
    const float* p = src + (size_t)(mt*16 + c) * 768 + kt*32 + quad*8;
    float4 v0 = *(const float4*)p;
    float4 v1 = *(const float4*)(p + 4);
    f16x8 o;
    o[0]=(_Float16)(v0.x*sc); o[1]=(_Float16)(v0.y*sc); o[2]=(_Float16)(v0.z*sc); o[3]=(_Float16)(v0.w*sc);
    o[4]=(_Float16)(v1.x*sc); o[5]=(_Float16)(v1.y*sc); o[6]=(_Float16)(v1.z*sc); o[7]=(_Float16)(v1.w*sc);
    *reinterpret_cast<f16x8*>(dst + ((size_t)t * 64 + lane) * 8) = o;
}

// ---- all 3 projections: 256x128 tiles, 8 waves, 288 blocks (v6, verified) ----
// bid < 192: C = x * [Wq;Wk]^T  (M=4096, N=1536) -> Qf/Kf frag layout
// bid >= 192: C = Wv * x^T      (M=768, N=4096)  -> Vkt 16x16 tile layout
__global__ __launch_bounds__(512) void gemm3(
    const _Float16* __restrict__ xf, const _Float16* __restrict__ wqkf,
    const _Float16* __restrict__ wvf,
    _Float16* __restrict__ Qf, _Float16* __restrict__ Kf, _Float16* __restrict__ Vkt)
{
    __shared__ _Float16 Ab[2][16*512];   // 32 KB (A: 16 row-units)
    __shared__ _Float16 Bb[2][8*512];    // 16 KB (B: 8 col-units)
    const int tid = threadIdx.x, lane = tid & 63, w = tid >> 6;
    const int c = lane & 15, quad = lane >> 4;

    const _Float16 *Af, *Bf;
    int mt0, nt0, mode;
    if ((int)blockIdx.x < 192) {
        int mt = blockIdx.x / 12, nt = blockIdx.x % 12;   // 16x12 tiles
        Af = xf; Bf = wqkf; mt0 = mt*16; nt0 = nt*8; mode = 0;
    } else {
        int v = blockIdx.x - 192;
        int mt = v / 32, nt = v % 32;                     // 3x32 tiles
        Af = wvf; Bf = xf; mt0 = mt*16; nt0 = nt*8; mode = 1;
    }

    auto stage = [&](int kt, int buf) {
#pragma unroll
        for (int u = 0; u < 3; ++u) {
            const int cc = w*3 + u;   // 0..23: 16 A-units then 8 B-units
            const _Float16* s = (cc < 16) ? Af + ((size_t)(mt0+cc)*24 + kt)*512
                                          : Bf + ((size_t)(nt0+cc-16)*24 + kt)*512;
            _Float16* d = (cc < 16) ? &Ab[buf][cc*512] : &Bb[buf][(cc-16)*512];
            dma16(s + lane*8, d);
        }
    };

    stage(0, 0);
    __syncthreads();

    f32x4 acc[4][4] = {};
    for (int kt = 0; kt < 24; ++kt) {
        const int cur = kt & 1;
        if (kt < 23) stage(kt+1, cur^1);
        f16x8 a[4], b[4];
#pragma unroll
        for (int i = 0; i < 4; ++i)
            a[i] = *(const f16x8*)(&Ab[cur][((w>>1)*4 + i)*512] + lane*8);
#pragma unroll
        for (int j = 0; j < 4; ++j)
            b[j] = *(const f16x8*)(&Bb[cur][((w&1)*4 + j)*512] + lane*8);
#pragma unroll
        for (int i = 0; i < 4; ++i)
#pragma unroll
            for (int j = 0; j < 4; ++j)
                acc[i][j] = __builtin_amdgcn_mfma_f32_16x16x32_f16(a[i], b[j], acc[i][j], 0,0,0);
        __syncthreads();
    }

    // epilogue: per-wave 32x32 transposes (buffers dead after last barrier)
    _Float16* L = &Ab[0][0] + w*1280;   // 32x40 halves per wave
#pragma unroll
    for (int i2 = 0; i2 < 2; ++i2)
#pragma unroll
        for (int j2 = 0; j2 < 2; ++j2) {
#pragma unroll
            for (int ii = 0; ii < 2; ++ii)
#pragma unroll
                for (int jj = 0; jj < 2; ++jj)
#pragma unroll
                    for (int r = 0; r < 4; ++r)
                        L[(ii*16 + quad*4 + r)*40 + jj*16 + c] =
                            (_Float16)acc[i2*2+ii][j2*2+jj][r];
#pragma unroll
            for (int ii = 0; ii < 2; ++ii) {
                const int mtg = mt0 + (w>>1)*4 + i2*2 + ii;   // 16-row unit
                if (mode == 0) {
                    f16x8 v = *(const f16x8*)(L + (ii*16 + c)*40 + quad*8);
                    const int nt32 = (nt0 + (w&1)*4)/2 + j2;  // 32-col unit
                    _Float16* dst = (nt32 < 24)
                        ? Qf + ((size_t)(mtg*24 + nt32)*64 + lane)*8
                        : Kf + ((size_t)(mtg*24 + nt32 - 24)*64 + lane)*8;
                    *(f16x8*)dst = v;
                } else {
#pragma unroll
                    for (int jj = 0; jj < 2; ++jj) {
                        f16x4 v4 = *(const f16x4*)(L + (ii*16 + c)*40 + jj*16 + quad*4);
                        const int kcu = nt0 + (w&1)*4 + j2*2 + jj;   // 16-key unit
                        *(f16x4*)(Vkt + ((size_t)kcu*48 + mtg)*256 + lane*4) = v4;
                    }
                }
            }
        }
}

// ---- pass 1: Lc[q,k] = log2( sum_h 2^{S2_h[q,k]} ) + log2(sqrt(768)) ----
// Barrier-free, LDS-free. Wave = (b, qt16, 128-key slice): Q for all 12
// heads resident (96 VGPR, capped by launch_bounds(256,4)); K streamed.
// Block = 4 waves, same (b, k-slice), consecutive q-tiles -> K reads L1-hit.
// Grid 1024 = 8 XCD x 128, swizzled so each XCD's blocks share K slices.
__global__ __launch_bounds__(256, 4) void dcalc(
    const _Float16* __restrict__ Qf, const _Float16* __restrict__ Kf,
    float* __restrict__ Lc)
{
    const int tid = threadIdx.x, lane = tid & 63, w = tid >> 6;
    const int rb = ((int)blockIdx.x & 7)*128 + ((int)blockIdx.x >> 3);
    const int u  = rb*4 + w;              // 0..4095
    const int qtl = u & 127;
    const int kks = (u >> 7) & 15;        // 8-subtile key slice
    const int b   = u >> 11;
    const int qt16 = b*128 + qtl;
    const int kb16 = b*128 + kks*8;       // first 16-key subtile (global units)

    // Q resident: all 12 heads (frags 2h, 2h+1), 96 VGPRs
    f16x8 qreg[24];
#pragma unroll
    for (int f = 0; f < 24; ++f)
        qreg[f] = *(const f16x8*)(Qf + ((size_t)(qt16*24 + f)*64 + lane)*8);

    const _Float16* Kp0 = Kf + ((size_t)kb16*24)*512 + (size_t)lane*8;
    float* Lp = Lc + ((size_t)(qt16*128 + kks*8))*256 + lane*4;

    for (int i = 0; i < 8; ++i) {
        const _Float16* Kp = Kp0 + (size_t)i*24*512;
        f32x4 D = {};
#pragma unroll
        for (int h = 0; h < 12; ++h) {
            f16x8 k0 = *(const f16x8*)(Kp + (2*h    )*512);
            f16x8 k1 = *(const f16x8*)(Kp + (2*h + 1)*512);
            f32x4 a = {};
            a = __builtin_amdgcn_mfma_f32_16x16x32_f16(k0, qreg[2*h    ], a, 0,0,0);
            a = __builtin_amdgcn_mfma_f32_16x16x32_f16(k1, qreg[2*h + 1], a, 0,0,0);
            // a[r] = S2^T[k = quad*4+r][q = c]  (log2 domain via Wq pre-scale)
#pragma unroll
            for (int r = 0; r < 4; ++r) D[r] += __builtin_amdgcn_exp2f(a[r]);
        }
        f32x4 L;
#pragma unroll
        for (int r = 0; r < 4; ++r)
            L[r] = __log2f(D[r]) + 4.792481250360578f;   // + log2(sqrt(768))
        *(f32x4*)(Lp + (size_t)i*256) = L;
    }
}

// ---- pass 2: per-head attention, barrier-free, LDS-free, no k-split ----
// Wave = (b, h, qt16), streams ALL 2048 keys (128 subtiles):
//   S2^T = mfma(K, Q)  ->  P^T[k][q] = 2^(S2 - Lc)  computed IN REGISTERS
//   (the S^T output lane layout IS the PV B-operand layout), then 4 PV
//   MFMAs against Vkt tiles. Output written once, f32, no partials.
// Block = 4 waves, same (b,h), consecutive q-tiles -> K/V reads L1-hit.
// Grid 768 = 8 XCD x 96 swizzled: each XCD owns 3 (b,h) K/V slices in L2.
__global__ __launch_bounds__(256) void attn2(
    const _Float16* __restrict__ Qf, const _Float16* __restrict__ Kf,
    const _Float16* __restrict__ Vkt, const float* __restrict__ Lc,
    float* __restrict__ out)
{
    const int tid = threadIdx.x, lane = tid & 63, w = tid >> 6;
    const int c = lane & 15, quad = lane >> 4;
    const int rb = ((int)blockIdx.x & 7)*96 + ((int)blockIdx.x >> 3);
    const int u  = rb*4 + w;              // 0..3071
    const int qtl = u & 127;
    const int v  = u >> 7;                // 0..23
    const int h  = v % 12;
    const int b  = v / 12;
    const int qt16 = b*128 + qtl;
    const int kb16 = b*128;

    // Q frags for head h (B-operand)
    f16x8 q0 = *(const f16x8*)(Qf + ((size_t)(qt16*24 + 2*h    )*64 + lane)*8);
    f16x8 q1 = *(const f16x8*)(Qf + ((size_t)(qt16*24 + 2*h + 1)*64 + lane)*8);

    const _Float16* Kp0 = Kf  + ((size_t)(kb16*24 + 2*h))*512 + (size_t)lane*8;
    const _Float16* Vp0 = Vkt + ((size_t)(kb16*48 + h*4))*256 + (size_t)lane*4;
    const float*    Lp0 = Lc  + ((size_t)qt16*128)*256 + lane*4;

    f32x4 o_acc[4] = {};   // out^T[d = dt*16 + quad*4 + r][q = c]

#pragma unroll 2
    for (int t = 0; t < 128; ++t) {
        const _Float16* Kp = Kp0 + (size_t)t*24*512;
        f16x8 k0 = *(const f16x8*)(Kp);
        f16x8 k1 = *(const f16x8*)(Kp + 512);
        f32x4 Lt = *(const f32x4*)(Lp0 + (size_t)t*256);
        f32x4 a = {};
        a = __builtin_amdgcn_mfma_f32_16x16x32_f16(k0, q0, a, 0,0,0);
        a = __builtin_amdgcn_mfma_f32_16x16x32_f16(k1, q1, a, 0,0,0);
        // a[r] = S2^T[k = t*16 + quad*4 + r][q = c]
        f16x4 pp;
#pragma unroll
        for (int r = 0; r < 4; ++r)
            pp[r] = (_Float16)__builtin_amdgcn_exp2f(a[r] - Lt[r]);
        const _Float16* Vp = Vp0 + (size_t)t*48*256;
#pragma unroll
        for (int dt = 0; dt < 4; ++dt) {
            f16x4 vt = *(const f16x4*)(Vp + dt*256);
            o_acc[dt] = __builtin_amdgcn_mfma_f32_16x16x16f16(vt, pp, o_acc[dt], 0,0,0);
        }
    }

    // epilogue: o_acc[dt][r] = out[q = qt*16 + c][d = h*64 + dt*16 + quad*4 + r]
    float* op = out + (size_t)(qt16*16 + c)*DIM + h*64 + quad*4;
#pragma unroll
    for (int dt = 0; dt < 4; ++dt)
        *(f32x4*)(op + dt*16) = o_acc[dt];
}

// ------------------------------- launch ----------------------------------
extern "C" void kernel_launch(void* const* d_in, const int* in_sizes, int n_in,
                              void* d_out, int out_size, void* d_ws, size_t ws_size,
                              hipStream_t stream)
{
    const float* x  = (const float*)d_in[0];
    const float* Wq = (const float*)d_in[1];
    const float* Wk = (const float*)d_in[2];
    const float* Wv = (const float*)d_in[3];

    _Float16* ws  = (_Float16*)d_ws;
    const size_t XS = (size_t)ROWS * DIM;   // 3145728
    const size_t WS = (size_t)DIM * DIM;    // 589824
    _Float16* xf   = ws;
    _Float16* wqf  = xf  + XS;              // wq+wk adjacent = stacked [Wq;Wk]
    _Float16* wkf  = wqf + WS;
    _Float16* wvf  = wkf + WS;
    _Float16* Qf   = wvf + WS;
    _Float16* Kf   = Qf  + XS;
    _Float16* Vkt  = Kf  + XS;
    float*    Lc   = (float*)(Vkt + XS);    // 256*128 tiles * 256 f32 = 33.5 MB

    cvt_all<<<2400, 256, 0, stream>>>(x, Wq, Wk, Wv, xf, wqf, wkf, wvf);
    gemm3<<<288, 512, 0, stream>>>(xf, wqf, wvf, Qf, Kf, Vkt);
    dcalc<<<1024, 256, 0, stream>>>(Qf, Kf, Lc);
    attn2<<<768, 256, 0, stream>>>(Qf, Kf, Vkt, Lc, (float*)d_out);
}

// Round 11
// 188.505 us; speedup vs baseline: 1.1602x; 1.1602x over previous
//
#include <hip/hip_runtime.h>

#define DIM 768
#define NHEADS 12
#define HDIM 64
#define BATCH 2
#define SEQ 2048
#define ROWS (BATCH*SEQ)   // 4096
#define KSPLIT 4

typedef __attribute__((ext_vector_type(8))) _Float16 f16x8;
typedef __attribute__((ext_vector_type(4))) _Float16 f16x4;
typedef __attribute__((ext_vector_type(2))) _Float16 f16x2;
typedef __attribute__((ext_vector_type(4))) float    f32x4;

// async global->LDS DMA, 16 B per lane; LDS dest must be wave-uniform base
__device__ __forceinline__ void dma16(const _Float16* g, _Float16* l) {
    __builtin_amdgcn_global_load_lds(
        (const __attribute__((address_space(1))) unsigned int*)g,
        (__attribute__((address_space(3))) unsigned int*)l, 16, 0, 0);
}

// ============================================================
// Fragment layout F(mt, kt): 16 rows x 32 cols of row-major M[R][C]:
//   frag[lane][j] = M[mt*16 + (lane&15)][kt*32 + (lane>>4)*8 + j]
// stored at dst[((mt*(C/32) + kt)*64 + lane)*8] (halves).
// V tile layout (for 16x16x16 PV MFMA): per 16-key chunk kc,
//   Vkt[((kc*48 + (h*4+dt))*64 + lane)*4] : tile[lane][j] =
//   V[d = (h*4+dt)*16 + (lane&15)][key = kc*16 + (lane>>4)*4 + j]
// ============================================================

// ---- all 4 fp32->f16 frag conversions in one launch (all have C=768) ----
// Wq is pre-scaled by log2(e): QK^T scores land in log2 domain, so the
// softmax exp is a single v_exp_f32 (2^x). Wq feeds ONLY Q. (verified v4/v5)
__global__ __launch_bounds__(256) void cvt_all(
    const float* __restrict__ x,  const float* __restrict__ wq,
    const float* __restrict__ wk, const float* __restrict__ wv,
    _Float16* __restrict__ xf,  _Float16* __restrict__ wqf,
    _Float16* __restrict__ wkf, _Float16* __restrict__ wvf)
{
    const int lane = threadIdx.x & 63;
    const int wid  = (blockIdx.x * 256 + threadIdx.x) >> 6;
    const float* src; _Float16* dst; int t;
    float sc = 1.0f;
    if (wid < 6144)      { src = x;  dst = xf;  t = wid;        }
    else if (wid < 7296) { src = wq; dst = wqf; t = wid - 6144; sc = 1.4426950408889634f; }
    else if (wid < 8448) { src = wk; dst = wkf; t = wid - 7296; }
    else                 { src = wv; dst = wvf; t = wid - 8448; }
    const int c = lane & 15, quad = lane >> 4;
    const int mt = t / 24, kt = t % 24;
    const float* p = src + (size_t)(mt*16 + c) * 768 + kt*32 + quad*8;
    float4 v0 = *(const float4*)p;
    float4 v1 = *(const float4*)(p + 4);
    f16x8 o;
    o[0]=(_Float16)(v0.x*sc); o[1]=(_Float16)(v0.y*sc); o[2]=(_Float16)(v0.z*sc); o[3]=(_Float16)(v0.w*sc);
    o[4]=(_Float16)(v1.x*sc); o[5]=(_Float16)(v1.y*sc); o[6]=(_Float16)(v1.z*sc); o[7]=(_Float16)(v1.w*sc);
    *reinterpret_cast<f16x8*>(dst + ((size_t)t * 64 + lane) * 8) = o;
}

// ---- all 3 projections: 256x128 tiles, 8 waves, 288 blocks (r5, verified) ----
// bid < 192: C = x * [Wq;Wk]^T  (M=4096, N=1536) -> Qf/Kf frag layout
// bid >= 192: C = Wv * x^T      (M=768, N=4096)  -> Vkt 16x16 tile layout
__global__ __launch_bounds__(512) void gemm3(
    const _Float16* __restrict__ xf, const _Float16* __restrict__ wqkf,
    const _Float16* __restrict__ wvf,
    _Float16* __restrict__ Qf, _Float16* __restrict__ Kf, _Float16* __restrict__ Vkt)
{
    __shared__ _Float16 Ab[2][16*512];   // 32 KB (A: 16 row-units)
    __shared__ _Float16 Bb[2][8*512];    // 16 KB (B: 8 col-units)
    const int tid = threadIdx.x, lane = tid & 63, w = tid >> 6;
    const int c = lane & 15, quad = lane >> 4;

    const _Float16 *Af, *Bf;
    int mt0, nt0, mode;
    if ((int)blockIdx.x < 192) {
        int mt = blockIdx.x / 12, nt = blockIdx.x % 12;   // 16x12 tiles
        Af = xf; Bf = wqkf; mt0 = mt*16; nt0 = nt*8; mode = 0;
    } else {
        int v = blockIdx.x - 192;
        int mt = v / 32, nt = v % 32;                     // 3x32 tiles
        Af = wvf; Bf = xf; mt0 = mt*16; nt0 = nt*8; mode = 1;
    }

    auto stage = [&](int kt, int buf) {
#pragma unroll
        for (int u = 0; u < 3; ++u) {
            const int cc = w*3 + u;   // 0..23: 16 A-units then 8 B-units
            const _Float16* s = (cc < 16) ? Af + ((size_t)(mt0+cc)*24 + kt)*512
                                          : Bf + ((size_t)(nt0+cc-16)*24 + kt)*512;
            _Float16* d = (cc < 16) ? &Ab[buf][cc*512] : &Bb[buf][(cc-16)*512];
            dma16(s + lane*8, d);
        }
    };

    stage(0, 0);
    __syncthreads();

    f32x4 acc[4][4] = {};
    for (int kt = 0; kt < 24; ++kt) {
        const int cur = kt & 1;
        if (kt < 23) stage(kt+1, cur^1);
        f16x8 a[4], b[4];
#pragma unroll
        for (int i = 0; i < 4; ++i)
            a[i] = *(const f16x8*)(&Ab[cur][((w>>1)*4 + i)*512] + lane*8);
#pragma unroll
        for (int j = 0; j < 4; ++j)
            b[j] = *(const f16x8*)(&Bb[cur][((w&1)*4 + j)*512] + lane*8);
#pragma unroll
        for (int i = 0; i < 4; ++i)
#pragma unroll
            for (int j = 0; j < 4; ++j)
                acc[i][j] = __builtin_amdgcn_mfma_f32_16x16x32_f16(a[i], b[j], acc[i][j], 0,0,0);
        __syncthreads();
    }

    // epilogue: per-wave 32x32 transposes (buffers dead after last barrier)
    _Float16* L = &Ab[0][0] + w*1280;   // 32x40 halves per wave
#pragma unroll
    for (int i2 = 0; i2 < 2; ++i2)
#pragma unroll
        for (int j2 = 0; j2 < 2; ++j2) {
#pragma unroll
            for (int ii = 0; ii < 2; ++ii)
#pragma unroll
                for (int jj = 0; jj < 2; ++jj)
#pragma unroll
                    for (int r = 0; r < 4; ++r)
                        L[(ii*16 + quad*4 + r)*40 + jj*16 + c] =
                            (_Float16)acc[i2*2+ii][j2*2+jj][r];
#pragma unroll
            for (int ii = 0; ii < 2; ++ii) {
                const int mtg = mt0 + (w>>1)*4 + i2*2 + ii;   // 16-row unit
                if (mode == 0) {
                    f16x8 v = *(const f16x8*)(L + (ii*16 + c)*40 + quad*8);
                    const int nt32 = (nt0 + (w&1)*4)/2 + j2;  // 32-col unit
                    _Float16* dst = (nt32 < 24)
                        ? Qf + ((size_t)(mtg*24 + nt32)*64 + lane)*8
                        : Kf + ((size_t)(mtg*24 + nt32 - 24)*64 + lane)*8;
                    *(f16x8*)dst = v;
                } else {
#pragma unroll
                    for (int jj = 0; jj < 2; ++jj) {
                        f16x4 v4 = *(const f16x4*)(L + (ii*16 + c)*40 + jj*16 + quad*4);
                        const int kcu = nt0 + (w&1)*4 + j2*2 + jj;   // 16-key unit
                        *(f16x4*)(Vkt + ((size_t)kcu*48 + mtg)*256 + lane*4) = v4;
                    }
                }
            }
        }
}

// ---- fused attention v10 = r4/v5 EXACT dataflow (89 us, best measured)
//      + XCD swizzle (v6: FETCH 52->19 MB) + s_setprio around MFMA (T5) ----
// grid: 512 blocks (2/CU), 512 thr (8 waves: qi=w>>2 in {0,1}, g=w&3).
// Block = 32 q-rows (2 qt) x 512 keys; 32 subtiles of 16 keys.
// LDS 50.7 KB (Kb 24K + Ps 10.5K + Pl 15K), ~112 regs/wave -> 2 blocks/CU.
// Wave (qi,g):
//   ph1: S^T = mfma(K, Q) heads 3g..3g+2 (log2 domain) -> exp2 in regs ->
//        one b128 partial-sum write to Ps (conflict-free quad*84+c*4 layout)
//   softmax: 4 b128 Ps reads, inv = rcp(sum*sqrt(768)), 3 b64 Pl writes (P^T)
//   ph2: out^T += mfma(Vtile, P^T), d-tile g, V direct from global (L2-hot)
// Per iter t: [ph1(t); Ps; ph2(t-1)] A [dma K(t+1); softmax; Pl; issue vv(t)] B
__global__ __launch_bounds__(512) __attribute__((amdgpu_waves_per_eu(4)))
void attn_kernel(
    const _Float16* __restrict__ Qf, const _Float16* __restrict__ Kf,
    const _Float16* __restrict__ Vkt,
    float* __restrict__ out,          // ks==0 partial (covers all elements)
    _Float16* __restrict__ part)      // [3][4096][768] f16, ks=1..3
{
    __shared__ __attribute__((aligned(16))) _Float16 Kb[24*512];        // 24 KB
    __shared__ __attribute__((aligned(16))) float    Ps[8][336];        // 10.5 KB
    __shared__ __attribute__((aligned(16))) _Float16 Pl[2][12][16][20]; // 15 KB
    const int tid = threadIdx.x, lane = tid & 63, w = tid >> 6;
    const int c = lane & 15, quad = lane >> 4;
    const int qi = w >> 2, g = w & 3;

    const int bid = blockIdx.x;
    const int rb = (bid & 7)*64 + (bid >> 3);   // XCD-chunk swizzle (bijective)
    const int qb = rb & 63;
    const int ks = (rb >> 6) & 3;
    const int b  = rb >> 8;
    const int qrow0 = b*SEQ + qb*32;
    const int qt16  = (qrow0 >> 4) + qi;
    const int kb16  = (b*SEQ + ks*(SEQ/KSPLIT)) >> 4;
    // Ps word offset: each 16-lane group touches one contiguous 256B region
    const int psoff = quad*84 + c*4;

    // Q frags (B-operand: b[lane][j] = Q[q=lane&15][d=quad*8+j]), heads 3g..3g+2
    f16x8 qreg[6];
#pragma unroll
    for (int u = 0; u < 6; ++u)
        qreg[u] = *(const f16x8*)(Qf + ((size_t)(qt16*24 + g*6 + u)*64 + lane)*8);

    // V base for this wave's d-tile: + (t*48 + h*4)*256 per (t,h)
    const _Float16* Vb0 = Vkt + ((size_t)kb16*48 + g)*256 + (size_t)lane*4;

    // preamble: DMA K(0) (all 8 waves, 3 frags each)
#pragma unroll
    for (int u = 0; u < 3; ++u)
        dma16(Kf + ((size_t)kb16*24 + w*3 + u)*512 + lane*8, &Kb[(w*3+u)*512]);
    __syncthreads();

    f32x4 o_acc[12] = {};   // 48 AGPRs: out^T[d=g*16+quad*4+r][q=c] per head
    f16x4 vv[12];           // V tiles for ph2, issued one iter ahead
    f32x4 e3[3];            // exp2(S^T) for own 3 heads

    for (int t = 0; t < 32; ++t) {
        // ---- ph1(t): S^T = K·Q for heads 3g..3g+2, exp2 in f32 regs ----
        __builtin_amdgcn_s_setprio(1);
#pragma unroll
        for (int hh = 0; hh < 3; ++hh) {
            f16x8 ka = *(const f16x8*)(&Kb[(g*6 + hh*2    )*512] + lane*8);
            f16x8 k2 = *(const f16x8*)(&Kb[(g*6 + hh*2 + 1)*512] + lane*8);
            f32x4 a = {};
            a = __builtin_amdgcn_mfma_f32_16x16x32_f16(ka, qreg[hh*2],   a, 0,0,0);
            a = __builtin_amdgcn_mfma_f32_16x16x32_f16(k2, qreg[hh*2+1], a, 0,0,0);
            // a[r] = S^T[k = quad*4+r][q = c]  (log2 domain via Wq pre-scale)
            f32x4 ee;
#pragma unroll
            for (int r = 0; r < 4; ++r) ee[r] = __builtin_amdgcn_exp2f(a[r]);
            e3[hh] = ee;
        }
        __builtin_amdgcn_s_setprio(0);
        {   // 3-head partial sum -> one b128 write
            f32x4 ps;
#pragma unroll
            for (int r = 0; r < 4; ++r) ps[r] = e3[0][r] + e3[1][r] + e3[2][r];
            *(f32x4*)&Ps[qi*4+g][psoff] = ps;
        }
        // ---- ph2(t-1): 12 heads x d-tile g over 16 keys ----
        if (t > 0) {
            __builtin_amdgcn_s_setprio(1);
#pragma unroll
            for (int h = 0; h < 12; ++h) {
                f16x4 pf = *(const f16x4*)&Pl[qi][h][c][quad*4];
                o_acc[h] = __builtin_amdgcn_mfma_f32_16x16x16f16(vv[h], pf, o_acc[h], 0,0,0);
            }
            __builtin_amdgcn_s_setprio(0);
        }
        __syncthreads();   // A: Ps visible; Kb/Pl readers done
        // ---- DMA K(t+1) (all 8 waves; Kb single-buffered, readers drained) ----
        if (t < 31) {
#pragma unroll
            for (int u = 0; u < 3; ++u)
                dma16(Kf + ((size_t)(kb16+t+1)*24 + w*3 + u)*512 + lane*8,
                      &Kb[(w*3+u)*512]);
        }
        // ---- softmax(t): total head-sum from 4 partials, P^T -> Pl ----
        {
            f32x4 s0 = *(const f32x4*)&Ps[qi*4+0][psoff];
            f32x4 s1 = *(const f32x4*)&Ps[qi*4+1][psoff];
            f32x4 s2 = *(const f32x4*)&Ps[qi*4+2][psoff];
            f32x4 s3 = *(const f32x4*)&Ps[qi*4+3][psoff];
            f32x4 inv;
#pragma unroll
            for (int r = 0; r < 4; ++r)
                inv[r] = __builtin_amdgcn_rcpf(
                    (s0[r]+s1[r]+s2[r]+s3[r]) * 27.712812921102035f);
#pragma unroll
            for (int hh = 0; hh < 3; ++hh) {
                f16x4 pw;
#pragma unroll
                for (int r = 0; r < 4; ++r) pw[r] = (_Float16)(e3[hh][r]*inv[r]);
                *(f16x4*)&Pl[qi][g*3+hh][c][quad*4] = pw;
            }
        }
        // ---- issue all 12 V tiles for ph2(t) (consumed next iter pre-A) ----
#pragma unroll
        for (int h = 0; h < 12; ++h)
            vv[h] = *(const f16x4*)(Vb0 + ((size_t)t*48 + h*4)*256);
        __syncthreads();   // B: Pl(t) visible; K(t+1) arrived
    }
    // ---- tail: ph2(31) ----
#pragma unroll
    for (int h = 0; h < 12; ++h) {
        f16x4 pf = *(const f16x4*)&Pl[qi][h][c][quad*4];
        o_acc[h] = __builtin_amdgcn_mfma_f32_16x16x16f16(vv[h], pf, o_acc[h], 0,0,0);
    }

    // ---- epilogue: o_acc[h][r] = out[q = c][d = h*64 + g*16 + quad*4 + r] ----
    if (ks == 0) {
#pragma unroll
        for (int h = 0; h < 12; ++h)
            *(f32x4*)(out + (size_t)(qrow0 + qi*16 + c)*DIM + h*64 + g*16 + quad*4)
                = o_acc[h];
    } else {
        _Float16* dst = part + (size_t)(ks - 1) * ROWS * DIM;
#pragma unroll
        for (int h = 0; h < 12; ++h) {
            f16x4 v;
#pragma unroll
            for (int r = 0; r < 4; ++r) v[r] = (_Float16)o_acc[h][r];
            *(f16x4*)(dst + (size_t)(qrow0 + qi*16 + c)*DIM + h*64 + g*16 + quad*4) = v;
        }
    }
}

// ---- out += sum of 3 f16 partials ----
__global__ __launch_bounds__(256) void reduce_add4(
    float* __restrict__ out, const _Float16* __restrict__ part, int n4)
{
    int i = blockIdx.x * 256 + threadIdx.x;
    if (i >= n4) return;
    float4 o = reinterpret_cast<float4*>(out)[i];
    const size_t N = (size_t)ROWS * DIM;
#pragma unroll
    for (int p = 0; p < 3; ++p) {
        f16x4 v = reinterpret_cast<const f16x4*>(part + p * N)[i];
        o.x += (float)v[0]; o.y += (float)v[1]; o.z += (float)v[2]; o.w += (float)v[3];
    }
    reinterpret_cast<float4*>(out)[i] = o;
}

// ------------------------------- launch ----------------------------------
extern "C" void kernel_launch(void* const* d_in, const int* in_sizes, int n_in,
                              void* d_out, int out_size, void* d_ws, size_t ws_size,
                              hipStream_t stream)
{
    const float* x  = (const float*)d_in[0];
    const float* Wq = (const float*)d_in[1];
    const float* Wk = (const float*)d_in[2];
    const float* Wv = (const float*)d_in[3];

    _Float16* ws  = (_Float16*)d_ws;
    const size_t XS = (size_t)ROWS * DIM;   // 3145728
    const size_t WS = (size_t)DIM * DIM;    // 589824
    _Float16* xf   = ws;
    _Float16* wqf  = xf  + XS;              // wq+wk adjacent = stacked [Wq;Wk]
    _Float16* wkf  = wqf + WS;
    _Float16* wvf  = wkf + WS;
    _Float16* Qf   = wvf + WS;
    _Float16* Kf   = Qf  + XS;
    _Float16* Vkt  = Kf  + XS;
    _Float16* part = Vkt + XS;              // 3 * XS f16 partials

    cvt_all<<<2400, 256, 0, stream>>>(x, Wq, Wk, Wv, xf, wqf, wkf, wvf);
    gemm3<<<288, 512, 0, stream>>>(xf, wqf, wvf, Qf, Kf, Vkt);
    attn_kernel<<<BATCH * KSPLIT * 64, 512, 0, stream>>>(
        Qf, Kf, Vkt, (float*)d_out, part);
    reduce_add4<<<(int)(XS/4 + 255)/256, 256, 0, stream>>>(
        (float*)d_out, part, (int)(XS/4));
}

// Round 12
// 178.132 us; speedup vs baseline: 1.2278x; 1.0582x over previous
//
#include <hip/hip_runtime.h>

#define DIM 768
#define NHEADS 12
#define HDIM 64
#define BATCH 2
#define SEQ 2048
#define ROWS (BATCH*SEQ)   // 4096
#define KSPLIT 4

typedef __attribute__((ext_vector_type(8))) _Float16 f16x8;
typedef __attribute__((ext_vector_type(4))) _Float16 f16x4;
typedef __attribute__((ext_vector_type(2))) _Float16 f16x2;
typedef __attribute__((ext_vector_type(4))) float    f32x4;

// async global->LDS DMA, 16 B per lane; LDS dest must be wave-uniform base
__device__ __forceinline__ void dma16(const _Float16* g, _Float16* l) {
    __builtin_amdgcn_global_load_lds(
        (const __attribute__((address_space(1))) unsigned int*)g,
        (__attribute__((address_space(3))) unsigned int*)l, 16, 0, 0);
}

// ============================================================
// Fragment layout F(mt, kt): 16 rows x 32 cols of row-major M[R][C]:
//   frag[lane][j] = M[mt*16 + (lane&15)][kt*32 + (lane>>4)*8 + j]
// stored at dst[((mt*(C/32) + kt)*64 + lane)*8] (halves).
// V tile layout (for 16x16x16 PV MFMA): per 16-key chunk kc,
//   Vkt[((kc*48 + (h*4+dt))*64 + lane)*4] : tile[lane][j] =
//   V[d = (h*4+dt)*16 + (lane&15)][key = kc*16 + (lane>>4)*4 + j]
// ============================================================

// ---- all 4 fp32->f16 frag conversions in one launch (all have C=768) ----
// Wq is pre-scaled by log2(e): QK^T scores land in log2 domain, so the
// softmax exp is a single v_exp_f32 (2^x). Wq feeds ONLY Q. (verified v4/v5)
__global__ __launch_bounds__(256) void cvt_all(
    const float* __restrict__ x,  const float* __restrict__ wq,
    const float* __restrict__ wk, const float* __restrict__ wv,
    _Float16* __restrict__ xf,  _Float16* __restrict__ wqf,
    _Float16* __restrict__ wkf, _Float16* __restrict__ wvf)
{
    const int lane = threadIdx.x & 63;
    const int wid  = (blockIdx.x * 256 + threadIdx.x) >> 6;
    const float* src; _Float16* dst; int t;
    float sc = 1.0f;
    if (wid < 6144)      { src = x;  dst = xf;  t = wid;        }
    else if (wid < 7296) { src = wq; dst = wqf; t = wid - 6144; sc = 1.4426950408889634f; }
    else if (wid < 8448) { src = wk; dst = wkf; t = wid - 7296; }
    else                 { src = wv; dst = wvf; t = wid - 8448; }
    const int c = lane & 15, quad = lane >> 4;
    const int mt = t / 24, kt = t % 24;
    const float* p = src + (size_t)(mt*16 + c) * 768 + kt*32 + quad*8;
    float4 v0 = *(const float4*)p;
    float4 v1 = *(const float4*)(p + 4);
    f16x8 o;
    o[0]=(_Float16)(v0.x*sc); o[1]=(_Float16)(v0.y*sc); o[2]=(_Float16)(v0.z*sc); o[3]=(_Float16)(v0.w*sc);
    o[4]=(_Float16)(v1.x*sc); o[5]=(_Float16)(v1.y*sc); o[6]=(_Float16)(v1.z*sc); o[7]=(_Float16)(v1.w*sc);
    *reinterpret_cast<f16x8*>(dst + ((size_t)t * 64 + lane) * 8) = o;
}

// ---- all 3 projections: 256x128 tiles, 8 waves, 288 blocks (r5, verified) ----
// bid < 192: C = x * [Wq;Wk]^T  (M=4096, N=1536) -> Qf/Kf frag layout
// bid >= 192: C = Wv * x^T      (M=768, N=4096)  -> Vkt 16x16 tile layout
__global__ __launch_bounds__(512) void gemm3(
    const _Float16* __restrict__ xf, const _Float16* __restrict__ wqkf,
    const _Float16* __restrict__ wvf,
    _Float16* __restrict__ Qf, _Float16* __restrict__ Kf, _Float16* __restrict__ Vkt)
{
    __shared__ _Float16 Ab[2][16*512];   // 32 KB (A: 16 row-units)
    __shared__ _Float16 Bb[2][8*512];    // 16 KB (B: 8 col-units)
    const int tid = threadIdx.x, lane = tid & 63, w = tid >> 6;
    const int c = lane & 15, quad = lane >> 4;

    const _Float16 *Af, *Bf;
    int mt0, nt0, mode;
    if ((int)blockIdx.x < 192) {
        int mt = blockIdx.x / 12, nt = blockIdx.x % 12;   // 16x12 tiles
        Af = xf; Bf = wqkf; mt0 = mt*16; nt0 = nt*8; mode = 0;
    } else {
        int v = blockIdx.x - 192;
        int mt = v / 32, nt = v % 32;                     // 3x32 tiles
        Af = wvf; Bf = xf; mt0 = mt*16; nt0 = nt*8; mode = 1;
    }

    auto stage = [&](int kt, int buf) {
#pragma unroll
        for (int u = 0; u < 3; ++u) {
            const int cc = w*3 + u;   // 0..23: 16 A-units then 8 B-units
            const _Float16* s = (cc < 16) ? Af + ((size_t)(mt0+cc)*24 + kt)*512
                                          : Bf + ((size_t)(nt0+cc-16)*24 + kt)*512;
            _Float16* d = (cc < 16) ? &Ab[buf][cc*512] : &Bb[buf][(cc-16)*512];
            dma16(s + lane*8, d);
        }
    };

    stage(0, 0);
    __syncthreads();

    f32x4 acc[4][4] = {};
    for (int kt = 0; kt < 24; ++kt) {
        const int cur = kt & 1;
        if (kt < 23) stage(kt+1, cur^1);
        f16x8 a[4], b[4];
#pragma unroll
        for (int i = 0; i < 4; ++i)
            a[i] = *(const f16x8*)(&Ab[cur][((w>>1)*4 + i)*512] + lane*8);
#pragma unroll
        for (int j = 0; j < 4; ++j)
            b[j] = *(const f16x8*)(&Bb[cur][((w&1)*4 + j)*512] + lane*8);
#pragma unroll
        for (int i = 0; i < 4; ++i)
#pragma unroll
            for (int j = 0; j < 4; ++j)
                acc[i][j] = __builtin_amdgcn_mfma_f32_16x16x32_f16(a[i], b[j], acc[i][j], 0,0,0);
        __syncthreads();
    }

    // epilogue: per-wave 32x32 transposes (buffers dead after last barrier)
    _Float16* L = &Ab[0][0] + w*1280;   // 32x40 halves per wave
#pragma unroll
    for (int i2 = 0; i2 < 2; ++i2)
#pragma unroll
        for (int j2 = 0; j2 < 2; ++j2) {
#pragma unroll
            for (int ii = 0; ii < 2; ++ii)
#pragma unroll
                for (int jj = 0; jj < 2; ++jj)
#pragma unroll
                    for (int r = 0; r < 4; ++r)
                        L[(ii*16 + quad*4 + r)*40 + jj*16 + c] =
                            (_Float16)acc[i2*2+ii][j2*2+jj][r];
#pragma unroll
            for (int ii = 0; ii < 2; ++ii) {
                const int mtg = mt0 + (w>>1)*4 + i2*2 + ii;   // 16-row unit
                if (mode == 0) {
                    f16x8 v = *(const f16x8*)(L + (ii*16 + c)*40 + quad*8);
                    const int nt32 = (nt0 + (w&1)*4)/2 + j2;  // 32-col unit
                    _Float16* dst = (nt32 < 24)
                        ? Qf + ((size_t)(mtg*24 + nt32)*64 + lane)*8
                        : Kf + ((size_t)(mtg*24 + nt32 - 24)*64 + lane)*8;
                    *(f16x8*)dst = v;
                } else {
#pragma unroll
                    for (int jj = 0; jj < 2; ++jj) {
                        f16x4 v4 = *(const f16x4*)(L + (ii*16 + c)*40 + jj*16 + quad*4);
                        const int kcu = nt0 + (w&1)*4 + j2*2 + jj;   // 16-key unit
                        *(f16x4*)(Vkt + ((size_t)kcu*48 + mtg)*256 + lane*4) = v4;
                    }
                }
            }
        }
}

// ---- fused attention v11 = EXACT v5/r4 kernel (89 us, best measured; no
//      XCD swizzle: spreading (b,ks) consumers across all 8 XCDs replicates
//      K/V in every L2 -> 8x aggregate L2 BW; swizzled variants all >=99 us) ----
// grid: 512 blocks (2/CU), 512 thr (8 waves: qi=w>>2 in {0,1}, g=w&3).
// Block = 32 q-rows (2 qt) x 512 keys; 32 subtiles of 16 keys.
// LDS 50.7 KB (Kb 24K + Ps 10.5K + Pl 15K), ~112 regs/wave -> 2 blocks/CU.
// Wave (qi,g):
//   ph1: S^T = mfma(K, Q) heads 3g..3g+2 (log2 domain) -> exp2 in regs ->
//        one b128 partial-sum write to Ps (conflict-free quad*84+c*4 layout)
//   softmax: 4 b128 Ps reads, inv = rcp(sum*sqrt(768)), 3 b64 Pl writes (P^T)
//   ph2: out^T += mfma(Vtile, P^T), d-tile g, V direct from global (L2-hot)
// Per iter t: [ph1(t); Ps; ph2(t-1)] A [dma K(t+1); softmax; Pl; issue vv(t)] B
__global__ __launch_bounds__(512) __attribute__((amdgpu_waves_per_eu(4)))
void attn_kernel(
    const _Float16* __restrict__ Qf, const _Float16* __restrict__ Kf,
    const _Float16* __restrict__ Vkt,
    float* __restrict__ out,          // ks==0 partial (covers all elements)
    _Float16* __restrict__ part)      // [3][4096][768] f16, ks=1..3
{
    __shared__ __attribute__((aligned(16))) _Float16 Kb[24*512];        // 24 KB
    __shared__ __attribute__((aligned(16))) float    Ps[8][336];        // 10.5 KB
    __shared__ __attribute__((aligned(16))) _Float16 Pl[2][12][16][20]; // 15 KB
    const int tid = threadIdx.x, lane = tid & 63, w = tid >> 6;
    const int c = lane & 15, quad = lane >> 4;
    const int qi = w >> 2, g = w & 3;

    const int bid = blockIdx.x;
    const int qb = bid & 63;
    const int ks = (bid >> 6) & 3;
    const int b  = bid >> 8;
    const int qrow0 = b*SEQ + qb*32;
    const int qt16  = (qrow0 >> 4) + qi;
    const int kb16  = (b*SEQ + ks*(SEQ/KSPLIT)) >> 4;
    // Ps word offset: each 16-lane group touches one contiguous 256B region
    const int psoff = quad*84 + c*4;

    // Q frags (B-operand: b[lane][j] = Q[q=lane&15][d=quad*8+j]), heads 3g..3g+2
    f16x8 qreg[6];
#pragma unroll
    for (int u = 0; u < 6; ++u)
        qreg[u] = *(const f16x8*)(Qf + ((size_t)(qt16*24 + g*6 + u)*64 + lane)*8);

    // V base for this wave's d-tile: + (t*48 + h*4)*256 per (t,h)
    const _Float16* Vb0 = Vkt + ((size_t)kb16*48 + g)*256 + (size_t)lane*4;

    // preamble: DMA K(0) (all 8 waves, 3 frags each)
#pragma unroll
    for (int u = 0; u < 3; ++u)
        dma16(Kf + ((size_t)kb16*24 + w*3 + u)*512 + lane*8, &Kb[(w*3+u)*512]);
    __syncthreads();

    f32x4 o_acc[12] = {};   // 48 AGPRs: out^T[d=g*16+quad*4+r][q=c] per head
    f16x4 vv[12];           // V tiles for ph2, issued one iter ahead
    f32x4 e3[3];            // exp2(S^T) for own 3 heads

    for (int t = 0; t < 32; ++t) {
        // ---- ph1(t): S^T = K·Q for heads 3g..3g+2, exp2 in f32 regs ----
#pragma unroll
        for (int hh = 0; hh < 3; ++hh) {
            f16x8 ka = *(const f16x8*)(&Kb[(g*6 + hh*2    )*512] + lane*8);
            f16x8 k2 = *(const f16x8*)(&Kb[(g*6 + hh*2 + 1)*512] + lane*8);
            f32x4 a = {};
            a = __builtin_amdgcn_mfma_f32_16x16x32_f16(ka, qreg[hh*2],   a, 0,0,0);
            a = __builtin_amdgcn_mfma_f32_16x16x32_f16(k2, qreg[hh*2+1], a, 0,0,0);
            // a[r] = S^T[k = quad*4+r][q = c]  (log2 domain via Wq pre-scale)
            f32x4 ee;
#pragma unroll
            for (int r = 0; r < 4; ++r) ee[r] = __builtin_amdgcn_exp2f(a[r]);
            e3[hh] = ee;
        }
        {   // 3-head partial sum -> one b128 write
            f32x4 ps;
#pragma unroll
            for (int r = 0; r < 4; ++r) ps[r] = e3[0][r] + e3[1][r] + e3[2][r];
            *(f32x4*)&Ps[qi*4+g][psoff] = ps;
        }
        // ---- ph2(t-1): 12 heads x d-tile g over 16 keys ----
        if (t > 0) {
#pragma unroll
            for (int h = 0; h < 12; ++h) {
                f16x4 pf = *(const f16x4*)&Pl[qi][h][c][quad*4];
                o_acc[h] = __builtin_amdgcn_mfma_f32_16x16x16f16(vv[h], pf, o_acc[h], 0,0,0);
            }
        }
        __syncthreads();   // A: Ps visible; Kb/Pl readers done
        // ---- DMA K(t+1) (all 8 waves; Kb single-buffered, readers drained) ----
        if (t < 31) {
#pragma unroll
            for (int u = 0; u < 3; ++u)
                dma16(Kf + ((size_t)(kb16+t+1)*24 + w*3 + u)*512 + lane*8,
                      &Kb[(w*3+u)*512]);
        }
        // ---- softmax(t): total head-sum from 4 partials, P^T -> Pl ----
        {
            f32x4 s0 = *(const f32x4*)&Ps[qi*4+0][psoff];
            f32x4 s1 = *(const f32x4*)&Ps[qi*4+1][psoff];
            f32x4 s2 = *(const f32x4*)&Ps[qi*4+2][psoff];
            f32x4 s3 = *(const f32x4*)&Ps[qi*4+3][psoff];
            f32x4 inv;
#pragma unroll
            for (int r = 0; r < 4; ++r)
                inv[r] = __builtin_amdgcn_rcpf(
                    (s0[r]+s1[r]+s2[r]+s3[r]) * 27.712812921102035f);
#pragma unroll
            for (int hh = 0; hh < 3; ++hh) {
                f16x4 pw;
#pragma unroll
                for (int r = 0; r < 4; ++r) pw[r] = (_Float16)(e3[hh][r]*inv[r]);
                *(f16x4*)&Pl[qi][g*3+hh][c][quad*4] = pw;
            }
        }
        // ---- issue all 12 V tiles for ph2(t) (consumed next iter pre-A) ----
#pragma unroll
        for (int h = 0; h < 12; ++h)
            vv[h] = *(const f16x4*)(Vb0 + ((size_t)t*48 + h*4)*256);
        __syncthreads();   // B: Pl(t) visible; K(t+1) arrived
    }
    // ---- tail: ph2(31) ----
#pragma unroll
    for (int h = 0; h < 12; ++h) {
        f16x4 pf = *(const f16x4*)&Pl[qi][h][c][quad*4];
        o_acc[h] = __builtin_amdgcn_mfma_f32_16x16x16f16(vv[h], pf, o_acc[h], 0,0,0);
    }

    // ---- epilogue: o_acc[h][r] = out[q = c][d = h*64 + g*16 + quad*4 + r] ----
    if (ks == 0) {
#pragma unroll
        for (int h = 0; h < 12; ++h)
            *(f32x4*)(out + (size_t)(qrow0 + qi*16 + c)*DIM + h*64 + g*16 + quad*4)
                = o_acc[h];
    } else {
        _Float16* dst = part + (size_t)(ks - 1) * ROWS * DIM;
#pragma unroll
        for (int h = 0; h < 12; ++h) {
            f16x4 v;
#pragma unroll
            for (int r = 0; r < 4; ++r) v[r] = (_Float16)o_acc[h][r];
            *(f16x4*)(dst + (size_t)(qrow0 + qi*16 + c)*DIM + h*64 + g*16 + quad*4) = v;
        }
    }
}

// ---- out += sum of 3 f16 partials ----
__global__ __launch_bounds__(256) void reduce_add4(
    float* __restrict__ out, const _Float16* __restrict__ part, int n4)
{
    int i = blockIdx.x * 256 + threadIdx.x;
    if (i >= n4) return;
    float4 o = reinterpret_cast<float4*>(out)[i];
    const size_t N = (size_t)ROWS * DIM;
#pragma unroll
    for (int p = 0; p < 3; ++p) {
        f16x4 v = reinterpret_cast<const f16x4*>(part + p * N)[i];
        o.x += (float)v[0]; o.y += (float)v[1]; o.z += (float)v[2]; o.w += (float)v[3];
    }
    reinterpret_cast<float4*>(out)[i] = o;
}

// ------------------------------- launch ----------------------------------
extern "C" void kernel_launch(void* const* d_in, const int* in_sizes, int n_in,
                              void* d_out, int out_size, void* d_ws, size_t ws_size,
                              hipStream_t stream)
{
    const float* x  = (const float*)d_in[0];
    const float* Wq = (const float*)d_in[1];
    const float* Wk = (const float*)d_in[2];
    const float* Wv = (const float*)d_in[3];

    _Float16* ws  = (_Float16*)d_ws;
    const size_t XS = (size_t)ROWS * DIM;   // 3145728
    const size_t WS = (size_t)DIM * DIM;    // 589824
    _Float16* xf   = ws;
    _Float16* wqf  = xf  + XS;              // wq+wk adjacent = stacked [Wq;Wk]
    _Float16* wkf  = wqf + WS;
    _Float16* wvf  = wkf + WS;
    _Float16* Qf   = wvf + WS;
    _Float16* Kf   = Qf  + XS;
    _Float16* Vkt  = Kf  + XS;
    _Float16* part = Vkt + XS;              // 3 * XS f16 partials

    cvt_all<<<2400, 256, 0, stream>>>(x, Wq, Wk, Wv, xf, wqf, wkf, wvf);
    gemm3<<<288, 512, 0, stream>>>(xf, wqf, wvf, Qf, Kf, Vkt);
    attn_kernel<<<BATCH * KSPLIT * 64, 512, 0, stream>>>(
        Qf, Kf, Vkt, (float*)d_out, part);
    reduce_add4<<<(int)(XS/4 + 255)/256, 256, 0, stream>>>(
        (float*)d_out, part, (int)(XS/4));
}